// Round 1
// baseline (162.182 us; speedup 1.0000x reference)
//
#include <hip/hip_runtime.h>

// CorpusSupportSets: one-hot-mask "matmuls" are row gathers. Fully fused,
// one wave (64 lanes) per sample, no LDS, no block barriers.
//
// Inputs (fp32): mask[BS,K], z[BS,DIM], SUPPORT_SETS[K,2*DIM], ALPHAS[K,2],
// LOGGAMMA[K,2].  Output (fp32): [BS,DIM].
// K=1000, DIM=768 fixed by the problem; BS derived from in_sizes.

constexpr int K   = 1000;
constexpr int DIM = 768;

__global__ __launch_bounds__(256) void css_kernel(
    const float* __restrict__ mask,
    const float* __restrict__ z,
    const float* __restrict__ ss,
    const float* __restrict__ alphas,
    const float* __restrict__ loggamma,
    float* __restrict__ out,
    int bs)
{
    const int gid  = blockIdx.x * blockDim.x + threadIdx.x;
    const int b    = gid >> 6;          // sample = wave index
    const int lane = threadIdx.x & 63;
    if (b >= bs) return;

    // ---- phase 1: find the one-hot index in mask[b, :] ----
    // 1000 floats = 250 float4 per row (4000 B, 16B-aligned since K%4==0).
    const float4* mrow = (const float4*)(mask + (size_t)b * K);
    int found = -1;
    #pragma unroll
    for (int i = 0; i < 4; ++i) {
        int e = lane + i * 64;
        if (e < 250) {
            float4 v = mrow[e];
            if (v.x != 0.f) found = e * 4 + 0;
            if (v.y != 0.f) found = e * 4 + 1;
            if (v.z != 0.f) found = e * 4 + 2;
            if (v.w != 0.f) found = e * 4 + 3;
        }
    }

    // Issue z loads before the index reduction to hide shuffle latency.
    const float4* zrow = (const float4*)(z + (size_t)b * DIM);
    float4 z4[3];
    #pragma unroll
    for (int i = 0; i < 3; ++i) z4[i] = zrow[lane + i * 64];

    // wave-wide max reduction -> every lane gets k
    #pragma unroll
    for (int off = 1; off < 64; off <<= 1)
        found = max(found, __shfl_xor(found, off, 64));
    const int k = (found < 0) ? 0 : found;

    // ---- phase 2: RBF gradient field ----
    // SUPPORT_SETS row k: pole 0 = [0:768), pole 1 = [768:1536)
    const float4* srow = (const float4*)(ss + (size_t)k * (2 * DIM));
    float4 d0[3], d1[3];
    float sqn0 = 0.f, sqn1 = 0.f;
    #pragma unroll
    for (int i = 0; i < 3; ++i) {
        float4 s0 = srow[lane + i * 64];
        float4 s1 = srow[192 + lane + i * 64];
        d0[i].x = z4[i].x - s0.x;  d0[i].y = z4[i].y - s0.y;
        d0[i].z = z4[i].z - s0.z;  d0[i].w = z4[i].w - s0.w;
        d1[i].x = z4[i].x - s1.x;  d1[i].y = z4[i].y - s1.y;
        d1[i].z = z4[i].z - s1.z;  d1[i].w = z4[i].w - s1.w;
        sqn0 += d0[i].x*d0[i].x + d0[i].y*d0[i].y + d0[i].z*d0[i].z + d0[i].w*d0[i].w;
        sqn1 += d1[i].x*d1[i].x + d1[i].y*d1[i].y + d1[i].z*d1[i].z + d1[i].w*d1[i].w;
    }
    #pragma unroll
    for (int off = 1; off < 64; off <<= 1) {
        sqn0 += __shfl_xor(sqn0, off, 64);
        sqn1 += __shfl_xor(sqn1, off, 64);
    }

    const float a0 = alphas[2 * k];
    const float a1 = alphas[2 * k + 1];
    const float g0 = expf(loggamma[2 * k]);
    const float g1 = expf(loggamma[2 * k + 1]);
    const float c0 = -2.f * a0 * g0 * expf(-g0 * sqn0);
    const float c1 = -2.f * a1 * g1 * expf(-g1 * sqn1);

    // grad = c0*d0 + c1*d1 ; dot = z . grad
    float4 g[3];
    float dot = 0.f;
    #pragma unroll
    for (int i = 0; i < 3; ++i) {
        g[i].x = c0 * d0[i].x + c1 * d1[i].x;
        g[i].y = c0 * d0[i].y + c1 * d1[i].y;
        g[i].z = c0 * d0[i].z + c1 * d1[i].z;
        g[i].w = c0 * d0[i].w + c1 * d1[i].w;
        dot += z4[i].x*g[i].x + z4[i].y*g[i].y + z4[i].z*g[i].z + z4[i].w*g[i].w;
    }
    #pragma unroll
    for (int off = 1; off < 64; off <<= 1) dot += __shfl_xor(dot, off, 64);

    // proj = grad - dot*z ; nsq = ||proj||^2
    float nsq = 0.f;
    #pragma unroll
    for (int i = 0; i < 3; ++i) {
        g[i].x -= dot * z4[i].x;
        g[i].y -= dot * z4[i].y;
        g[i].z -= dot * z4[i].z;
        g[i].w -= dot * z4[i].w;
        nsq += g[i].x*g[i].x + g[i].y*g[i].y + g[i].z*g[i].z + g[i].w*g[i].w;
    }
    #pragma unroll
    for (int off = 1; off < 64; off <<= 1) nsq += __shfl_xor(nsq, off, 64);

    const float inv = 1.f / sqrtf(nsq);
    float4* orow = (float4*)(out + (size_t)b * DIM);
    #pragma unroll
    for (int i = 0; i < 3; ++i) {
        float4 r;
        r.x = g[i].x * inv; r.y = g[i].y * inv;
        r.z = g[i].z * inv; r.w = g[i].w * inv;
        orow[lane + i * 64] = r;
    }
}

extern "C" void kernel_launch(void* const* d_in, const int* in_sizes, int n_in,
                              void* d_out, int out_size, void* d_ws, size_t ws_size,
                              hipStream_t stream) {
    const float* mask     = (const float*)d_in[0];
    const float* z        = (const float*)d_in[1];
    const float* ss       = (const float*)d_in[2];
    const float* alphas   = (const float*)d_in[3];
    const float* loggamma = (const float*)d_in[4];
    float* out = (float*)d_out;

    const int bs = in_sizes[1] / DIM;           // 16384
    const int waves_per_block = 256 / 64;       // 4 samples per block
    const int grid = (bs + waves_per_block - 1) / waves_per_block;
    css_kernel<<<grid, 256, 0, stream>>>(mask, z, ss, alphas, loggamma, out, bs);
}